// Round 2
// baseline (1679.549 us; speedup 1.0000x reference)
//
#include <hip/hip_runtime.h>

#define N_NODES 100000
#define N_EDGES 1600000
#define HD 128
#define NLAYERS 4
#define COUT 40
#define BN_EPS 1e-5f
constexpr int NB = (N_NODES + 255) / 256;   // 391 scan blocks

typedef _Float16 half8 __attribute__((ext_vector_type(8)));
typedef _Float16 half2v __attribute__((ext_vector_type(2)));
typedef float floatx4 __attribute__((ext_vector_type(4)));

// ---- weight transpose + fp32->fp16 prep: Wt[n][k] so B-fragments are contiguous ----
__global__ void prep_kernel(const float* __restrict__ W_in,
                            const float* __restrict__ Wl,
                            const float* __restrict__ Wr,
                            const float* __restrict__ W_out,
                            _Float16* __restrict__ Wt_in,    // [128][128]
                            _Float16* __restrict__ Wt_cat,   // [4][128][256] (k<128->Wl, k>=128->Wr)
                            _Float16* __restrict__ Wt_out)   // [48][128], rows(n) >= 40 zero
{
    int tid = blockIdx.x * blockDim.x + threadIdx.x;
    int stride = gridDim.x * blockDim.x;
    for (int idx = tid; idx < 128 * 128; idx += stride) {
        int n = idx >> 7, k = idx & 127;
        Wt_in[idx] = (_Float16)W_in[k * 128 + n];
    }
    for (int idx = tid; idx < 4 * 128 * 256; idx += stride) {
        int i = idx >> 15;
        int r = idx & 32767;
        int n = r >> 8, k = r & 255;
        Wt_cat[idx] = (_Float16)((k < 128) ? Wl[i * 16384 + k * 128 + n]
                                           : Wr[i * 16384 + (k - 128) * 128 + n]);
    }
    for (int idx = tid; idx < 48 * 128; idx += stride) {
        int n = idx >> 7, k = idx & 127;
        Wt_out[idx] = (n < COUT) ? (_Float16)W_out[k * COUT + n] : (_Float16)0.f;
    }
}

// ---- CSR build ----
__global__ void hist_kernel(const int* __restrict__ dst, int* __restrict__ deg) {
    int tid = blockIdx.x * blockDim.x + threadIdx.x;
    int stride = gridDim.x * blockDim.x;
    for (int e = tid; e < N_EDGES; e += stride)
        atomicAdd(&deg[dst[e]], 1);
}

__global__ __launch_bounds__(256) void scan1_kernel(const int* __restrict__ deg, int* __restrict__ bsum) {
    __shared__ int s[256];
    int i = blockIdx.x * 256 + threadIdx.x;
    s[threadIdx.x] = (i < N_NODES) ? deg[i] : 0;
    __syncthreads();
    for (int off = 128; off > 0; off >>= 1) {
        if (threadIdx.x < off) s[threadIdx.x] += s[threadIdx.x + off];
        __syncthreads();
    }
    if (threadIdx.x == 0) bsum[blockIdx.x] = s[0];
}

__global__ void scan2_kernel(int* __restrict__ bsum, int* __restrict__ rs) {
    // one wave: exclusive scan of NB block sums
    int lane = threadIdx.x;
    int run = 0;
    for (int base = 0; base < NB; base += 64) {
        int i = base + lane;
        int orig = (i < NB) ? bsum[i] : 0;
        int v = orig;
        #pragma unroll
        for (int off = 1; off < 64; off <<= 1) {
            int t = __shfl_up(v, off);
            if (lane >= off) v += t;
        }
        int total = __shfl(v, 63);
        if (i < NB) bsum[i] = v - orig + run;
        run += total;
    }
    if (lane == 0) rs[N_NODES] = run;  // == N_EDGES
}

__global__ __launch_bounds__(256) void scan3_kernel(int* __restrict__ rs, int* __restrict__ cur,
                                                    const int* __restrict__ bsum) {
    __shared__ int s[256];
    int i = blockIdx.x * 256 + threadIdx.x;
    int v = (i < N_NODES) ? rs[i] : 0;
    s[threadIdx.x] = v;
    __syncthreads();
    for (int off = 1; off < 256; off <<= 1) {
        int t = 0;
        if ((int)threadIdx.x >= off) t = s[threadIdx.x - off];
        __syncthreads();
        s[threadIdx.x] += t;
        __syncthreads();
    }
    if (i < N_NODES) {
        int excl = s[threadIdx.x] - v + bsum[blockIdx.x];
        rs[i] = excl;
        cur[i] = excl;
    }
}

__global__ void scatter_kernel(const int* __restrict__ src, const int* __restrict__ dst,
                               int* __restrict__ cur, int* __restrict__ ssrc) {
    int tid = blockIdx.x * blockDim.x + threadIdx.x;
    int stride = gridDim.x * blockDim.x;
    for (int e = tid; e < N_EDGES; e += stride) {
        int p = atomicAdd(&cur[dst[e]], 1);
        ssrc[p] = src[e];
    }
}

// ---- mean aggregation: one wave per destination node, lanes cover 128 cols ----
__global__ __launch_bounds__(256) void aggregate_kernel(const _Float16* __restrict__ H,
                                                        const int* __restrict__ rs,
                                                        const int* __restrict__ ssrc,
                                                        _Float16* __restrict__ AGG) {
    int wid = (blockIdx.x * 256 + threadIdx.x) >> 6;
    if (wid >= N_NODES) return;
    int lane = threadIdx.x & 63;
    int e0 = rs[wid], e1 = rs[wid + 1];
    float a0 = 0.f, a1 = 0.f;
    for (int e = e0; e < e1; ++e) {
        int s = ssrc[e];
        half2v v = *(const half2v*)(H + (long)s * HD + lane * 2);
        a0 += (float)v[0];
        a1 += (float)v[1];
    }
    float inv = 1.f / (float)max(e1 - e0, 1);
    half2v o = { (_Float16)(a0 * inv), (_Float16)(a1 * inv) };
    *(half2v*)(AGG + (long)wid * HD + lane * 2) = o;
}

// ---- MFMA GEMM: Y[r][c] = concat(A0,A1)[r][:] . Wt[c][:] + bias[c] ----
// A-fragment: lane holds A[row0 + (lane&15)][quad*8 + j]  (16B contiguous)
// B-fragment: lane holds Wt[c*16 + (lane&15)][quad*8 + j] (16B contiguous)
// C-fragment: lane holds C[row0 + quad*4 + i][c*16 + (lane&15)]
template <int CT, int KS, bool HAS_A1, bool A_F32, bool OUT_F32>
__global__ __launch_bounds__(256) void gemm_kernel(const void* __restrict__ A0v,
                                                   const _Float16* __restrict__ A1,
                                                   const _Float16* __restrict__ Wt,
                                                   const float* __restrict__ bias,
                                                   void* __restrict__ Yv,
                                                   int out_stride, int ncols) {
    constexpr int K = KS * 32;
    int wave = threadIdx.x >> 6;
    int lane = threadIdx.x & 63;
    int quad = lane >> 4;
    int l16 = lane & 15;
    int row_base = (blockIdx.x * 4 + wave) * 32;
    if (row_base >= N_NODES) return;

    floatx4 acc[2][CT];
    #pragma unroll
    for (int rt = 0; rt < 2; ++rt)
        #pragma unroll
        for (int c = 0; c < CT; ++c)
            acc[rt][c] = (floatx4){0.f, 0.f, 0.f, 0.f};

    #pragma unroll
    for (int s = 0; s < KS; ++s) {
        int kk = s * 32 + quad * 8;
        half8 afrag[2];
        #pragma unroll
        for (int rt = 0; rt < 2; ++rt) {
            int r = row_base + rt * 16 + l16;
            if (r > N_NODES - 1) r = N_NODES - 1;  // clamp read, store guarded below
            if (A_F32) {
                const float* p = (const float*)A0v + (long)r * 128 + kk;
                floatx4 f0 = *(const floatx4*)p;
                floatx4 f1 = *(const floatx4*)(p + 4);
                #pragma unroll
                for (int j = 0; j < 4; ++j) {
                    afrag[rt][j]     = (_Float16)f0[j];
                    afrag[rt][4 + j] = (_Float16)f1[j];
                }
            } else {
                const _Float16* p;
                if (HAS_A1 && kk >= 128) p = A1 + (long)r * 128 + (kk - 128);
                else                     p = (const _Float16*)A0v + (long)r * 128 + kk;
                afrag[rt] = *(const half8*)p;
            }
        }
        #pragma unroll
        for (int c = 0; c < CT; ++c) {
            half8 bfrag = *(const half8*)(Wt + (c * 16 + l16) * K + kk);
            #pragma unroll
            for (int rt = 0; rt < 2; ++rt)
                acc[rt][c] = __builtin_amdgcn_mfma_f32_16x16x32_f16(afrag[rt], bfrag, acc[rt][c], 0, 0, 0);
        }
    }

    #pragma unroll
    for (int c = 0; c < CT; ++c) {
        int col = c * 16 + l16;
        if (col >= ncols) continue;
        float bv = bias[col];
        #pragma unroll
        for (int rt = 0; rt < 2; ++rt) {
            #pragma unroll
            for (int i = 0; i < 4; ++i) {
                int r = row_base + rt * 16 + quad * 4 + i;
                if (r < N_NODES) {
                    float v = acc[rt][c][i] + bv;
                    if (OUT_F32) ((float*)Yv)[(long)r * out_stride + col] = v;
                    else         ((_Float16*)Yv)[(long)r * out_stride + col] = (_Float16)v;
                }
            }
        }
    }
}

// ---- BatchNorm: per-block partial column sums (no atomics, no init needed) ----
__global__ __launch_bounds__(256) void bn_stats_kernel(const _Float16* __restrict__ Y,
                                                       float* __restrict__ psum,
                                                       float* __restrict__ psq) {
    int col = threadIdx.x & 127;
    int half = threadIdx.x >> 7;
    float s = 0.f, q = 0.f;
    for (int r = blockIdx.x * 2 + half; r < N_NODES; r += gridDim.x * 2) {
        float v = (float)Y[(long)r * HD + col];
        s += v; q += v * v;
    }
    __shared__ float ls[256], lq[256];
    ls[threadIdx.x] = s; lq[threadIdx.x] = q;
    __syncthreads();
    if (half == 0) {
        psum[blockIdx.x * 128 + col] = s + ls[128 + col];
        psq [blockIdx.x * 128 + col] = q + lq[128 + col];
    }
}

__global__ void bn_reduce_kernel(const float* __restrict__ psum, const float* __restrict__ psq,
                                 const float* __restrict__ g, const float* __restrict__ b,
                                 float* __restrict__ ss, int nb) {
    int col = threadIdx.x;  // 128 threads
    float s = 0.f, q = 0.f;
    for (int i = 0; i < nb; ++i) { s += psum[i * 128 + col]; q += psq[i * 128 + col]; }
    float m = s / (float)N_NODES;
    float v = q / (float)N_NODES - m * m;
    float sc = g[col] * rsqrtf(v + BN_EPS);
    ss[col] = sc;
    ss[128 + col] = b[col] - m * sc;
}

__global__ __launch_bounds__(256) void bn_apply_kernel(const _Float16* __restrict__ Y,
                                                       const float* __restrict__ ss,
                                                       _Float16* __restrict__ H) {
    long total = (long)N_NODES * HD / 8;
    for (long t = (long)blockIdx.x * blockDim.x + threadIdx.x; t < total;
         t += (long)gridDim.x * blockDim.x) {
        long base = t * 8;
        int col0 = (int)(base & 127);
        half8 in = *(const half8*)(Y + base);
        half8 outv;
        #pragma unroll
        for (int j = 0; j < 8; ++j) {
            float v = (float)in[j];
            float r = v * ss[col0 + j] + ss[128 + col0 + j];
            outv[j] = (_Float16)fmaxf(r, 0.f);
        }
        *(half8*)(H + base) = outv;
    }
}

extern "C" void kernel_launch(void* const* d_in, const int* in_sizes, int n_in,
                              void* d_out, int out_size, void* d_ws, size_t ws_size,
                              hipStream_t stream) {
    (void)in_sizes; (void)n_in; (void)out_size; (void)ws_size;
    const float* x       = (const float*)d_in[0];
    const float* W_in    = (const float*)d_in[1];
    const float* b_in    = (const float*)d_in[2];
    const float* g_in    = (const float*)d_in[3];
    const float* beta_in = (const float*)d_in[4];
    const float* Wl      = (const float*)d_in[5];
    const float* bl      = (const float*)d_in[6];
    const float* Wr      = (const float*)d_in[7];
    const float* g_bn    = (const float*)d_in[8];
    const float* b_bn    = (const float*)d_in[9];
    const float* W_out   = (const float*)d_in[10];
    const float* b_out   = (const float*)d_in[11];
    const int*   ei      = (const int*)d_in[12];
    const int* esrc = ei;
    const int* edst = ei + N_EDGES;
    float* out = (float*)d_out;

    char* w = (char*)d_ws;
    auto alloc = [&](size_t bytes) -> char* {
        char* p = w; w += (bytes + 255) & ~(size_t)255; return p;
    };
    int* rs           = (int*)alloc((N_NODES + 1) * sizeof(int));  // deg -> row_start
    int* cur          = (int*)alloc(N_NODES * sizeof(int));
    int* bsum         = (int*)alloc(512 * sizeof(int));
    int* ssrc         = (int*)alloc(N_EDGES * sizeof(int));
    _Float16* Wt_in   = (_Float16*)alloc(128 * 128 * 2);
    _Float16* Wt_cat  = (_Float16*)alloc(4 * 128 * 256 * 2);
    _Float16* Wt_out  = (_Float16*)alloc(48 * 128 * 2);
    _Float16* hbuf    = (_Float16*)alloc((size_t)N_NODES * HD * 2);
    _Float16* agg     = (_Float16*)alloc((size_t)N_NODES * HD * 2);
    _Float16* ybuf    = (_Float16*)alloc((size_t)N_NODES * HD * 2);
    float* psum       = (float*)alloc(256 * 128 * 4);
    float* psq        = (float*)alloc(256 * 128 * 4);
    float* ss         = (float*)alloc(256 * 4);

    hipMemsetAsync(rs, 0, (N_NODES + 1) * sizeof(int), stream);
    prep_kernel<<<256, 256, 0, stream>>>(W_in, Wl, Wr, W_out, Wt_in, Wt_cat, Wt_out);
    hist_kernel<<<2048, 256, 0, stream>>>(edst, rs);
    scan1_kernel<<<NB, 256, 0, stream>>>(rs, bsum);
    scan2_kernel<<<1, 64, 0, stream>>>(bsum, rs);
    scan3_kernel<<<NB, 256, 0, stream>>>(rs, cur, bsum);
    scatter_kernel<<<2048, 256, 0, stream>>>(esrc, edst, cur, ssrc);

    const int GB = (N_NODES + 127) / 128;  // 782 blocks, 128 rows each

    // input layer: y = x @ W_in + b_in ; h = relu(bn(y))
    gemm_kernel<8, 4, false, true, false><<<GB, 256, 0, stream>>>(x, nullptr, Wt_in, b_in, ybuf, HD, HD);
    bn_stats_kernel<<<256, 256, 0, stream>>>(ybuf, psum, psq);
    bn_reduce_kernel<<<1, 128, 0, stream>>>(psum, psq, g_in, beta_in, ss, 256);
    bn_apply_kernel<<<1600, 256, 0, stream>>>(ybuf, ss, hbuf);

    for (int i = 0; i < NLAYERS; ++i) {
        aggregate_kernel<<<N_NODES / 4, 256, 0, stream>>>(hbuf, rs, ssrc, agg);
        gemm_kernel<8, 8, true, false, false><<<GB, 256, 0, stream>>>(agg, hbuf, Wt_cat + i * 128 * 256,
                                                                      bl + i * 128, ybuf, HD, HD);
        if (i < NLAYERS - 1) {
            bn_stats_kernel<<<256, 256, 0, stream>>>(ybuf, psum, psq);
            bn_reduce_kernel<<<1, 128, 0, stream>>>(psum, psq, g_bn + i * 128, b_bn + i * 128, ss, 256);
            bn_apply_kernel<<<1600, 256, 0, stream>>>(ybuf, ss, hbuf);
        }
    }

    // output layer: out = h4 @ W_out + b_out  (h4 lives in ybuf, no BN on last layer)
    gemm_kernel<3, 4, false, false, true><<<GB, 256, 0, stream>>>(ybuf, nullptr, Wt_out, b_out, out, COUT, COUT);
}